// Round 6
// baseline (293.459 us; speedup 1.0000x reference)
//
#include <hip/hip_runtime.h>
#include <stdint.h>

#define BATCH 16
#define CIN   32
#define HH    128
#define WW    128
#define BO    32
#define OCH   128   // 4*BO
#define NCH   16    // h-chunks (8 rows each)
#define DEPTH 64    // handoff ring depth (power of 2)

// ws: [0,4096) progress ints
//     [4096, +RINGSZ) tagged handoff ring
//     [4096+RINGSZ, +I2SSZ) i2s buffer (fp32)
#define RINGSZ ((size_t)BATCH * NCH * DEPTH * BO * 8)
#define I2SSZ  ((size_t)BATCH * HH * WW * OCH * 4)

// ================= K1: i2s GEMM  (i2s[b,row,t,o] = b2+b1 + sum_c W2*x_skew) ==
__global__ __launch_bounds__(256, 4) void i2s_gemm(
    const float* __restrict__ x, const float* __restrict__ W2g,
    const float* __restrict__ b2, const float* __restrict__ b1,
    float* __restrict__ i2s)
{
    const int tid = threadIdx.x;
    const int bx  = blockIdx.x;
    const int b   = bx >> 7;
    const int row = bx & 127;

    __shared__ __attribute__((aligned(16))) float xs[CIN][WW];    // skewed x row
    __shared__ __attribute__((aligned(16))) float w2s[CIN][OCH];  // W2^T [c][o]
    __shared__ float bs[OCH];

    // stage W2^T (c-major loop: coalesced LDS writes)
    for (int i = tid; i < CIN * OCH; i += 256) {
        const int c = i >> 7, o = i & 127;
        w2s[c][o] = W2g[o * CIN + c];
    }
    if (tid < OCH) bs[tid] = b2[tid] + b1[tid];
    // stage skewed x: xs[c][t] = (t>=row) ? x[b,c,row,t-row] : 0
    for (int i = tid; i < CIN * WW; i += 256) {
        const int c = i >> 7, t = i & 127;
        xs[c][t] = (t >= row)
            ? x[((size_t)(b * CIN + c) * HH + row) * WW + (t - row)] : 0.f;
    }
    __syncthreads();

    const int tm = tid >> 4;          // t-block (8 t)
    const int tn = tid & 15;          // o-block (8 o)
    const int t0 = tm * 8, o0 = tn * 8;

    float bv[8];
    *(float4*)&bv[0] = *(const float4*)&bs[o0];
    *(float4*)&bv[4] = *(const float4*)&bs[o0 + 4];
    float acc[8][8];
#pragma unroll
    for (int i = 0; i < 8; ++i)
#pragma unroll
        for (int jj = 0; jj < 8; ++jj) acc[i][jj] = bv[jj];

    for (int c = 0; c < CIN; ++c) {
        float a[8], wv[8];
        *(float4*)&a[0]  = *(const float4*)&xs[c][t0];
        *(float4*)&a[4]  = *(const float4*)&xs[c][t0 + 4];
        *(float4*)&wv[0] = *(const float4*)&w2s[c][o0];
        *(float4*)&wv[4] = *(const float4*)&w2s[c][o0 + 4];
#pragma unroll
        for (int i = 0; i < 8; ++i)
#pragma unroll
            for (int jj = 0; jj < 8; ++jj)
                acc[i][jj] = fmaf(a[i], wv[jj], acc[i][jj]);
    }

    float* dst = i2s + (size_t)(b * HH + row) * WW * OCH;
#pragma unroll
    for (int i = 0; i < 8; ++i) {
        *(float4*)&dst[(size_t)(t0 + i) * OCH + o0]     = *(float4*)&acc[i][0];
        *(float4*)&dst[(size_t)(t0 + i) * OCH + o0 + 4] = *(float4*)&acc[i][4];
    }
}

// ================= K2: scan (1 channel/lane, 64 weight regs) ================
__global__ __launch_bounds__(1024, 4) void diag_lstm_scan_v6(
    const float* __restrict__ W1g, float* __restrict__ out,
    int* __restrict__ progress, unsigned long long* __restrict__ hand,
    const float* __restrict__ i2s)
{
    const int tid = threadIdx.x;
    const int l   = tid & 63;
    const int w   = tid >> 6;        // wave 0..15
    const int r   = w >> 1;          // local row 0..7
    const int sub = w & 1;
    const int ll  = sub * 64 + l;    // output channel o = ll
    const int blk = blockIdx.x;
    const int b = (blk & 7) + ((blk >> 7) << 3);   // XCD-affinity remap
    const int k = (blk >> 3) & (NCH - 1);
    const int row = k * 8 + r;

    __shared__ __attribute__((aligned(16))) float phs[2][9][BO];
    __shared__ __attribute__((aligned(16))) float gbuf[8][OCH];

    for (int i = tid; i < 2 * 9 * BO; i += 1024) ((float*)phs)[i] = 0.f;

    // recurrent weights for own channel: 64 VGPRs total
    float w1p[CIN], w1c[CIN];
#pragma unroll
    for (int c = 0; c < CIN; ++c) {
        w1p[c] = W1g[(ll * CIN + c) * 2 + 0];
        w1c[c] = W1g[(ll * CIN + c) * 2 + 1];
    }

    const int j = l & 31;
    const bool cellactive = (sub == 0) && (l < 32);
    float pc = 0.f, ob0 = 0.f, ob1 = 0.f, ob2 = 0.f;
    float* outrow = out + ((size_t)(b * BO + j) * HH + row) * WW;

    const float* myi2s = i2s + (size_t)(b * HH + row) * WW * OCH + ll;

    const int kprev = (k > 0) ? k - 1 : 0;
    const unsigned long long* srcbase =
        hand + (size_t)((b * NCH + kprev) * DEPTH) * BO + j;
    unsigned long long* dstbase =
        hand + (size_t)((b * NCH + k) * DEPTH) * BO + j;
    int* myprog   = progress + (b * NCH + k);
    int* consprog = myprog + 1;

    unsigned long long pre = 0ull;
    float ip0 = myi2s[0];
    float ip1 = myi2s[(size_t)1 * OCH];

    __syncthreads();

    for (int t = 0; t < WW; ++t) {
        const int par = t & 1;

        // ---- boundary poll: BOTH row-0 waves, idempotent (overlaps others' gates)
        if ((w <= 1) && k > 0 && t > 0) {
            unsigned long long q = pre;
            while (__any((unsigned)(q >> 32) != (unsigned)t)) {
                q = __hip_atomic_load(&srcbase[(size_t)((t - 1) & (DEPTH - 1)) * BO],
                                      __ATOMIC_RELAXED, __HIP_MEMORY_SCOPE_AGENT);
            }
            if (l < 32) phs[par][0][l] = __uint_as_float((unsigned)q);
            pre = __hip_atomic_load(&srcbase[(size_t)(t & (DEPTH - 1)) * BO],
                                    __ATOMIC_RELAXED, __HIP_MEMORY_SCOPE_AGENT);
            asm volatile("s_waitcnt lgkmcnt(0)" ::: "memory");
        }

        // ---- gates: 1 channel/lane, 64 FMA on register weights ----
        float g = ip0;
        ip0 = ip1;
        {
            const int tn2 = (t + 2 < WW) ? t + 2 : WW - 1;
            ip1 = myi2s[(size_t)tn2 * OCH];
        }
        {
            const float4* pv4 = (const float4*)&phs[par][r][0];      // h(row-1) prev
            const float4* qv4 = (const float4*)&phs[par][r + 1][0];  // h(row)   prev
#pragma unroll
            for (int cc = 0; cc < CIN / 4; ++cc) {
                const float4 pv = pv4[cc];
                const float4 qv = qv4[cc];
                g = fmaf(w1p[4 * cc + 0], pv.x, g);
                g = fmaf(w1p[4 * cc + 1], pv.y, g);
                g = fmaf(w1p[4 * cc + 2], pv.z, g);
                g = fmaf(w1p[4 * cc + 3], pv.w, g);
                g = fmaf(w1c[4 * cc + 0], qv.x, g);
                g = fmaf(w1c[4 * cc + 1], qv.y, g);
                g = fmaf(w1c[4 * cc + 2], qv.z, g);
                g = fmaf(w1c[4 * cc + 3], qv.w, g);
            }
        }
        gbuf[r][ll] = g;
        __syncthreads();   // barrier A: gates published

        // ---- cell update (even waves, lanes < 32) ----
        if (cellactive) {
            if (w == 14 && k < NCH - 1 && (t & 15) == 0 && t >= 48) {
                while (__hip_atomic_load(consprog, __ATOMIC_RELAXED,
                                         __HIP_MEMORY_SCOPE_AGENT) < t - 47) { }
            }
            const float go = gbuf[r][j];
            const float gf = gbuf[r][32 + j];
            const float gi = gbuf[r][64 + j];
            const float gg = gbuf[r][96 + j];
            const float so = 1.f / (1.f + __expf(-go));
            const float sf = 1.f / (1.f + __expf(-gf));
            const float si = 1.f / (1.f + __expf(-gi));
            const float tg = 2.f / (1.f + __expf(-2.f * gg)) - 1.f;
            const float nc = sf * pc + si * tg;
            const float th = 2.f / (1.f + __expf(-2.f * nc)) - 1.f;
            const float nh = so * th;
            pc = nc;
            phs[par ^ 1][r + 1][j] = nh;

            const int ph4 = t & 3;
            if (ph4 == 0) ob0 = nh;
            else if (ph4 == 1) ob1 = nh;
            else if (ph4 == 2) ob2 = nh;
            else *(float4*)(outrow + (t - 3)) = make_float4(ob0, ob1, ob2, nh);

            if (r == 7 && k < NCH - 1) {   // handoff: tag t+1 into slot t&63
                unsigned long long q = ((unsigned long long)(unsigned)(t + 1) << 32)
                                     | (unsigned long long)__float_as_uint(nh);
                __hip_atomic_store(&dstbase[(size_t)(t & (DEPTH - 1)) * BO], q,
                                   __ATOMIC_RELAXED, __HIP_MEMORY_SCOPE_AGENT);
            }
            if (w == 0 && l == 0) {
                __hip_atomic_store(myprog, t + 1, __ATOMIC_RELAXED,
                                   __HIP_MEMORY_SCOPE_AGENT);
            }
        }
        __syncthreads();   // barrier B: phs[par^1] published
    }
}

// ===================== fallback (R4, proven, ws-lean) =====================
__global__ __launch_bounds__(512, 2) void diag_lstm_scan_v4(
    const float* __restrict__ x, const float* __restrict__ W2g,
    const float* __restrict__ b2, const float* __restrict__ W1g,
    const float* __restrict__ b1, float* __restrict__ out,
    int* __restrict__ progress, unsigned long long* __restrict__ hand)
{
    const int tid = threadIdx.x;
    const int l   = tid & 63;
    const int w   = tid >> 6;
    const int blk = blockIdx.x;
    const int b = (blk & 7) + ((blk >> 7) << 3);
    const int k = (blk >> 3) & (NCH - 1);
    const int row = k * 8 + w;

    __shared__ __attribute__((aligned(16))) float phs[2][9][BO];
    __shared__ __attribute__((aligned(16))) float xbuf[8][CIN];
    __shared__ __attribute__((aligned(16))) float gbuf[8][OCH];

    for (int i = tid; i < 2 * 9 * BO; i += 512) ((float*)phs)[i] = 0.f;

    const int o0 = 2 * l, o1 = 2 * l + 1;
    float w2a[CIN], w2b[CIN], w1pa[CIN], w1ca[CIN], w1pb[CIN], w1cb[CIN];
#pragma unroll
    for (int c = 0; c < CIN; ++c) {
        w2a[c]  = W2g[o0 * CIN + c];
        w2b[c]  = W2g[o1 * CIN + c];
        w1pa[c] = W1g[(o0 * CIN + c) * 2 + 0];
        w1ca[c] = W1g[(o0 * CIN + c) * 2 + 1];
        w1pb[c] = W1g[(o1 * CIN + c) * 2 + 0];
        w1cb[c] = W1g[(o1 * CIN + c) * 2 + 1];
    }
    const float biasA = b2[o0] + b1[o0];
    const float biasB = b2[o1] + b1[o1];

    const int j = l & 31;
    float pc = 0.f, ob0 = 0.f, ob1 = 0.f, ob2 = 0.f;
    float* outrow = out + ((size_t)(b * BO + j) * HH + row) * WW;

    const int kprev = (k > 0) ? k - 1 : 0;
    const unsigned long long* srcbase =
        hand + (size_t)((b * NCH + kprev) * DEPTH) * BO + j;
    unsigned long long* dstbase =
        hand + (size_t)((b * NCH + k) * DEPTH) * BO + j;
    int* myprog   = progress + (b * NCH + k);
    int* consprog = myprog + 1;

    unsigned long long pre = 0ull;
    __syncthreads();

    for (int t = 0; t < WW; ++t) {
        const int par = t & 1;
        if (l < 32) {
            const int wp = t - row;
            xbuf[w][l] = (wp >= 0)
                ? x[((size_t)(b * CIN + l) * HH + row) * WW + wp] : 0.f;
        }
        if (w == 0 && k > 0) {
            if (t > 0) {
                unsigned long long q = pre;
                while (__any((unsigned)(q >> 32) != (unsigned)t)) {
                    q = __hip_atomic_load(&srcbase[(size_t)((t - 1) & (DEPTH - 1)) * BO],
                                          __ATOMIC_RELAXED, __HIP_MEMORY_SCOPE_AGENT);
                }
                if (l < 32) phs[par][0][l] = __uint_as_float((unsigned)q);
            }
            pre = __hip_atomic_load(&srcbase[(size_t)(t & (DEPTH - 1)) * BO],
                                    __ATOMIC_RELAXED, __HIP_MEMORY_SCOPE_AGENT);
        }
        asm volatile("s_waitcnt lgkmcnt(0)" ::: "memory");

        float ga = biasA, gb = biasB;
        {
            const float4* xb4 = (const float4*)(&xbuf[w][0]);
            const float4* pv4 = (const float4*)(&phs[par][w][0]);
            const float4* qv4 = (const float4*)(&phs[par][w + 1][0]);
#pragma unroll
            for (int cc = 0; cc < CIN / 4; ++cc) {
                const float4 xv = xb4[cc];
                const float4 pv = pv4[cc];
                const float4 qv = qv4[cc];
                const float* xs = (const float*)&xv;
                const float* ps = (const float*)&pv;
                const float* qs = (const float*)&qv;
#pragma unroll
                for (int ci = 0; ci < 4; ++ci) {
                    const int c = 4 * cc + ci;
                    ga = fmaf(w2a[c],  xs[ci], ga);
                    gb = fmaf(w2b[c],  xs[ci], gb);
                    ga = fmaf(w1pa[c], ps[ci], ga);
                    gb = fmaf(w1pb[c], ps[ci], gb);
                    ga = fmaf(w1ca[c], qs[ci], ga);
                    gb = fmaf(w1cb[c], qs[ci], gb);
                }
            }
        }
        *(float2*)&gbuf[w][o0] = make_float2(ga, gb);
        asm volatile("s_waitcnt lgkmcnt(0)" ::: "memory");

        if (l < 32) {
            if (w == 7 && k < NCH - 1 && (t & 15) == 0 && t >= 48) {
                while (__hip_atomic_load(consprog, __ATOMIC_RELAXED,
                                         __HIP_MEMORY_SCOPE_AGENT) < t - 47) { }
            }
            const float go = gbuf[w][l];
            const float gf = gbuf[w][32 + l];
            const float gi = gbuf[w][64 + l];
            const float gg = gbuf[w][96 + l];
            const float so = 1.f / (1.f + __expf(-go));
            const float sf = 1.f / (1.f + __expf(-gf));
            const float si = 1.f / (1.f + __expf(-gi));
            const float tg = 2.f / (1.f + __expf(-2.f * gg)) - 1.f;
            const float nc = sf * pc + si * tg;
            const float th = 2.f / (1.f + __expf(-2.f * nc)) - 1.f;
            const float nh = so * th;
            pc = nc;
            phs[par ^ 1][w + 1][l] = nh;

            const int ph4 = t & 3;
            if (ph4 == 0) ob0 = nh;
            else if (ph4 == 1) ob1 = nh;
            else if (ph4 == 2) ob2 = nh;
            else *(float4*)(outrow + (t - 3)) = make_float4(ob0, ob1, ob2, nh);

            if (w == 7 && k < NCH - 1) {
                unsigned long long q = ((unsigned long long)(unsigned)(t + 1) << 32)
                                     | (unsigned long long)__float_as_uint(nh);
                __hip_atomic_store(&dstbase[(size_t)(t & (DEPTH - 1)) * BO], q,
                                   __ATOMIC_RELAXED, __HIP_MEMORY_SCOPE_AGENT);
            }
            if (w == 0 && l == 0) {
                __hip_atomic_store(myprog, t + 1, __ATOMIC_RELAXED,
                                   __HIP_MEMORY_SCOPE_AGENT);
            }
        }
        __syncthreads();
    }
}

extern "C" void kernel_launch(void* const* d_in, const int* in_sizes, int n_in,
                              void* d_out, int out_size, void* d_ws, size_t ws_size,
                              hipStream_t stream) {
    const float* x  = (const float*)d_in[0];
    const float* W2 = (const float*)d_in[1];
    const float* b2 = (const float*)d_in[2];
    const float* W1 = (const float*)d_in[3];
    const float* b1 = (const float*)d_in[4];
    float* out = (float*)d_out;

    int* progress = (int*)d_ws;
    unsigned long long* hand = (unsigned long long*)((char*)d_ws + 4096);
    float* i2s = (float*)((char*)d_ws + 4096 + RINGSZ);

    const size_t need = 4096 + RINGSZ + I2SSZ;

    // clear progress + ring tags (stale tags alias valid ones across replays)
    hipMemsetAsync(d_ws, 0, 4096 + RINGSZ, stream);

    if (ws_size >= need) {
        hipLaunchKernelGGL(i2s_gemm, dim3(BATCH * HH), dim3(256), 0, stream,
                           x, W2, b2, b1, i2s);
        hipLaunchKernelGGL(diag_lstm_scan_v6, dim3(BATCH * NCH), dim3(1024), 0, stream,
                           W1, out, progress, hand, i2s);
    } else {
        hipLaunchKernelGGL(diag_lstm_scan_v4, dim3(BATCH * NCH), dim3(512), 0, stream,
                           x, W2, b2, W1, b1, out, progress, hand);
    }
}